// Round 2
// baseline (638.791 us; speedup 1.0000x reference)
//
#include <hip/hip_runtime.h>
#include <hip/hip_bf16.h>

// ReasoningMultiHeadAttention: B=4 S=2048 HID=1024 NH=16 DH=64
// All d_in / d_out are FP32 (reference is jnp.float32). We convert to bf16
// during LDS staging, MFMA-accumulate in fp32, blend/bias in fp32.
// Pipeline:
//   qg = (x@Wq+bq)*(1-m) + (x@Wqr+bqr)*m   [gemm<true,...>]   (bf16 out, ws)
//   kg = (x@Wk+bk)*(1-m) + (x@Wkr+bkr)*m   [gemm<true,...>]   (bf16 out, ws)
//   v  =  x@Wv+bv                           [gemm<false,...>] (bf16 out, ws)
//   per-token 16x16 cross-head attn + scrambled reshape       (bf16 out, ws)
//   out = attn_rs@Wo + bo                   [gemm<false,A_BF16,OUT_F32>] fp32
// ws: qg | kg | v | attn_rs  (4 x 16 MB = 64 MB)

typedef __attribute__((ext_vector_type(8))) short short8;
typedef __attribute__((ext_vector_type(4))) short short4v;
typedef __attribute__((ext_vector_type(4))) float f32x4;

#define NTOK 8192
#define HIDDIM 1024
#define BM 128
#define BN 128
#define BK 64
#define LDK 72   // padded LDS K-stride (144B): 2-way bank alias only (free)

__device__ __forceinline__ float b2f(const __hip_bfloat16 v) {
  return __bfloat162float(v);
}
__device__ __forceinline__ short f2bs(float f) {
  __hip_bfloat16 h = __float2bfloat16(f);
  return *reinterpret_cast<short*>(&h);
}

template<bool GATED, bool A_BF16, bool OUT_F32>
__global__ __launch_bounds__(256) void gemm_kernel(
    const void* __restrict__ Av,
    const float* __restrict__ W1, const float* __restrict__ B1,
    const float* __restrict__ W2, const float* __restrict__ B2,
    const float* __restrict__ MASK,
    void* __restrict__ OUTv)
{
  __shared__ short lA[BM][LDK];
  __shared__ short lB[BN][LDK];

  const int m0 = blockIdx.x * BM;
  const int n0 = blockIdx.y * BN;
  const int tid = threadIdx.x;
  const int lane = tid & 63;
  const int w = tid >> 6;
  const int wr = (w >> 1) * 64;   // wave row offset in tile
  const int wc = (w & 1) * 64;    // wave col offset in tile
  const int lrow = lane & 15;
  const int lkhi = (lane >> 4) << 3;

  f32x4 acc1[4][4] = {};
  f32x4 acc2[4][4] = {};

  auto run_pass = [&](const float* __restrict__ W, f32x4 (&acc)[4][4]) {
    for (int kt = 0; kt < HIDDIM / BK; kt++) {
      const int k0 = kt * BK;
      // ---- stage A tile (128 x 64) ----
      if (A_BF16) {
        const short* A = (const short*)Av;
        #pragma unroll
        for (int i = 0; i < 4; i++) {
          const int li = tid + i * 256;          // 0..1023
          const int row = li >> 3, cb = (li & 7) << 3;
          *reinterpret_cast<short8*>(&lA[row][cb]) =
              *reinterpret_cast<const short8*>(&A[(size_t)(m0 + row) * HIDDIM + k0 + cb]);
        }
      } else {
        const float* A = (const float*)Av;
        #pragma unroll
        for (int i = 0; i < 8; i++) {
          const int li = tid + i * 256;          // 0..2047
          const int row = li >> 4, c4 = (li & 15) << 2;
          const f32x4 a4 =
              *reinterpret_cast<const f32x4*>(&A[(size_t)(m0 + row) * HIDDIM + k0 + c4]);
          short4v s4;
          #pragma unroll
          for (int j = 0; j < 4; j++) s4[j] = f2bs(a4[j]);
          *reinterpret_cast<short4v*>(&lA[row][c4]) = s4;
        }
      }
      // ---- stage B tile transposed: lB[n][k] from fp32 W[k][n] ----
      #pragma unroll
      for (int i = 0; i < 8; i++) {
        const int li = tid + i * 256;            // 0..2047
        const int kk = li >> 5, n4 = (li & 31) << 2;
        const f32x4 wv =
            *reinterpret_cast<const f32x4*>(&W[(size_t)(k0 + kk) * HIDDIM + n0 + n4]);
        #pragma unroll
        for (int j = 0; j < 4; j++) lB[n4 + j][kk] = f2bs(wv[j]);
      }
      __syncthreads();
      #pragma unroll
      for (int kk = 0; kk < BK / 32; kk++) {
        const int lk = kk * 32 + lkhi;
        short8 af[4], bf[4];
        #pragma unroll
        for (int m = 0; m < 4; m++)
          af[m] = *reinterpret_cast<short8*>(&lA[wr + m * 16 + lrow][lk]);
        #pragma unroll
        for (int n = 0; n < 4; n++)
          bf[n] = *reinterpret_cast<short8*>(&lB[wc + n * 16 + lrow][lk]);
        #pragma unroll
        for (int m = 0; m < 4; m++) {
          #pragma unroll
          for (int n = 0; n < 4; n++)
            acc[m][n] = __builtin_amdgcn_mfma_f32_16x16x32_bf16(af[m], bf[n], acc[m][n], 0, 0, 0);
        }
      }
      __syncthreads();
    }
  };

  run_pass(W1, acc1);
  if (GATED) run_pass(W2, acc2);

  // Epilogue. C/D layout (m89-verified): col = lane&15, row = (lane>>4)*4 + reg
  #pragma unroll
  for (int m = 0; m < 4; m++) {
    const int rbase = m0 + wr + m * 16 + ((lane >> 4) << 2);
    #pragma unroll
    for (int n = 0; n < 4; n++) {
      const int col = n0 + wc + n * 16 + lrow;
      const float bias1 = B1[col];
      float bias2 = 0.f;
      if (GATED) bias2 = B2[col];
      #pragma unroll
      for (int r = 0; r < 4; r++) {
        const int row = rbase + r;
        float val = acc1[m][n][r] + bias1;
        if (GATED) {
          const float mk = MASK[row];
          val = val * (1.f - mk) + (acc2[m][n][r] + bias2) * mk;
        }
        const size_t oidx = (size_t)row * HIDDIM + col;
        if (OUT_F32) ((float*)OUTv)[oidx] = val;
        else ((__hip_bfloat16*)OUTv)[oidx] = __float2bfloat16(val);
      }
    }
  }
}

// Per-token 16x16 cross-head attention. One block per token.
// scores[h][e] = (q[h,:].k[e,:])/8 ; softmax over e ; out[h,d] = sum_e a[h][e] v[e,d]
// Output written pre-scrambled: global row = b*2048 + h*128 + s/16,
//                               col = (s%16)*64 + d
__global__ __launch_bounds__(256) void attn_kernel(
    const __hip_bfloat16* __restrict__ Q, const __hip_bfloat16* __restrict__ K,
    const __hip_bfloat16* __restrict__ V, __hip_bfloat16* __restrict__ O)
{
  const int t = blockIdx.x;          // token id
  const int b = t >> 11, s = t & 2047;
  __shared__ float sQ[16][68], sK[16][68], sV[16][68];
  __shared__ float sA[16][17];
  const int tid = threadIdx.x;
  const size_t tb = (size_t)t * HIDDIM;

  #pragma unroll
  for (int i = 0; i < 4; i++) {
    const int idx = tid + i * 256;
    const int h = idx >> 6, d = idx & 63;
    sQ[h][d] = b2f(Q[tb + idx]);
    sK[h][d] = b2f(K[tb + idx]);
    sV[h][d] = b2f(V[tb + idx]);
  }
  __syncthreads();

  const int h = tid >> 4, e = tid & 15;
  float sc = 0.f;
  #pragma unroll
  for (int d = 0; d < 64; d++) sc += sQ[h][d] * sK[e][d];
  sc *= 0.125f;   // 1/sqrt(64)

  float mx = sc;
  mx = fmaxf(mx, __shfl_xor(mx, 1));
  mx = fmaxf(mx, __shfl_xor(mx, 2));
  mx = fmaxf(mx, __shfl_xor(mx, 4));
  mx = fmaxf(mx, __shfl_xor(mx, 8));
  const float p = __expf(sc - mx);
  float sm = p;
  sm += __shfl_xor(sm, 1);
  sm += __shfl_xor(sm, 2);
  sm += __shfl_xor(sm, 4);
  sm += __shfl_xor(sm, 8);
  sA[h][e] = p / sm;
  __syncthreads();

  const size_t ob = ((size_t)b * 2048 + (s >> 4)) * HIDDIM + ((s & 15) << 6);
  #pragma unroll
  for (int i = 0; i < 4; i++) {
    const int idx = tid + i * 256;
    const int hh = idx >> 6, d = idx & 63;
    float o = 0.f;
    #pragma unroll
    for (int e2 = 0; e2 < 16; e2++) o += sA[hh][e2] * sV[e2][d];
    O[ob + (size_t)hh * 128 * HIDDIM + d] = __float2bfloat16(o);
  }
}

extern "C" void kernel_launch(void* const* d_in, const int* in_sizes, int n_in,
                              void* d_out, int out_size, void* d_ws, size_t ws_size,
                              hipStream_t stream) {
  (void)in_sizes; (void)n_in; (void)out_size; (void)ws_size;
  const float* x   = (const float*)d_in[0];
  const float* rm  = (const float*)d_in[1];
  const float* Wq  = (const float*)d_in[2];
  const float* bq  = (const float*)d_in[3];
  const float* Wk  = (const float*)d_in[4];
  const float* bk  = (const float*)d_in[5];
  const float* Wv  = (const float*)d_in[6];
  const float* bv  = (const float*)d_in[7];
  const float* Wqr = (const float*)d_in[8];
  const float* bqr = (const float*)d_in[9];
  const float* Wkr = (const float*)d_in[10];
  const float* bkr = (const float*)d_in[11];
  const float* Wo  = (const float*)d_in[12];
  const float* bo  = (const float*)d_in[13];

  const size_t P = (size_t)NTOK * HIDDIM;   // elements per bf16 intermediate
  __hip_bfloat16* qg = (__hip_bfloat16*)d_ws;
  __hip_bfloat16* kg = qg + P;
  __hip_bfloat16* vv = kg + P;
  __hip_bfloat16* ar = vv + P;   // 64 MB total

  dim3 grid(NTOK / BM, HIDDIM / BN), blk(256);
  gemm_kernel<true, false, false><<<grid, blk, 0, stream>>>(x, Wq, bq, Wqr, bqr, rm, qg);
  gemm_kernel<true, false, false><<<grid, blk, 0, stream>>>(x, Wk, bk, Wkr, bkr, rm, kg);
  gemm_kernel<false, false, false><<<grid, blk, 0, stream>>>(x, Wv, bv, nullptr, nullptr, nullptr, vv);
  attn_kernel<<<dim3(NTOK), blk, 0, stream>>>(qg, kg, vv, ar);
  gemm_kernel<false, true, true><<<grid, blk, 0, stream>>>(ar, Wo, bo, nullptr, nullptr, nullptr,
                                                           d_out);
}

// Round 3
// 178.357 us; speedup vs baseline: 3.5815x; 3.5815x over previous
//
#include <hip/hip_runtime.h>
#include <hip/hip_bf16.h>

// ReasoningMultiHeadAttention: B=4 S=2048 HID=1024 NH=16 DH=64. All I/O fp32.
// prep1: W{q,qr,k,kr,v} -> bf16 W^T, pre-swizzled (k ^= (n&7)<<3 per 64-blk)
// proj (one dispatch, z=0,1,2): qg/kg (gated, dual-acc shared A) and v
// attn: per-token 16x16 cross-head attention, writes swizzled+scrambled ar
// prep2: Wo -> WoT (into dead qg region)
// out_gemm: ar @ Wo + bo -> fp32 d_out, both operands via global_load_lds
// ws: [WT5 | ar] [qg/WoT] [kg] [vv]  = 67.1 MB (same footprint as round 2)

typedef __attribute__((ext_vector_type(8))) short short8;
typedef __attribute__((ext_vector_type(4))) short short4v;
typedef __attribute__((ext_vector_type(4))) float f32x4;

#define NTOK 8192
#define HID 1024
#define P_ELEMS (NTOK * HID)
#define WT_ELEMS (HID * HID)

__device__ __forceinline__ short f2bs(float f) {
  __hip_bfloat16 h = __float2bfloat16(f);
  return *reinterpret_cast<short*>(&h);
}
__device__ __forceinline__ float bs2f(short s) {
  __hip_bfloat16 h;
  *reinterpret_cast<short*>(&h) = s;
  return __bfloat162float(h);
}
__device__ __forceinline__ void gload_lds16(const void* g, void* l) {
  __builtin_amdgcn_global_load_lds(
      (const __attribute__((address_space(1))) void*)g,
      (__attribute__((address_space(3))) void*)l, 16, 0, 0);
}

// ---------------- prep: W (fp32 [k][n]) -> bf16 W^T swizzled ----------------
// OUT[n*HID + ((k & ~63) | ((k & 63) ^ ((n&7)<<3)))] = bf16(W[k][n])
__global__ __launch_bounds__(256) void transpose_kernel(
    const float* __restrict__ W0, const float* __restrict__ W1,
    const float* __restrict__ W2, const float* __restrict__ W3,
    const float* __restrict__ W4, short* __restrict__ OUTbase)
{
  const int z = blockIdx.z;
  const float* W = z == 0 ? W0 : z == 1 ? W1 : z == 2 ? W2 : z == 3 ? W3 : W4;
  short* OUT = OUTbase + (size_t)z * WT_ELEMS;
  __shared__ short sT[64][68];
  const int k0 = blockIdx.x * 64, n0 = blockIdx.y * 64;
  const int tid = threadIdx.x;
  #pragma unroll
  for (int i = 0; i < 4; i++) {
    const int li = tid + i * 256;
    const int kr = li >> 4, c4 = (li & 15) << 2;
    const f32x4 wv = *reinterpret_cast<const f32x4*>(&W[(size_t)(k0 + kr) * HID + n0 + c4]);
    short4v s4;
    #pragma unroll
    for (int j = 0; j < 4; j++) s4[j] = f2bs(wv[j]);
    *reinterpret_cast<short4v*>(&sT[kr][c4]) = s4;
  }
  __syncthreads();
  #pragma unroll
  for (int i = 0; i < 4; i++) {
    const int li = tid + i * 256;
    const int nr = li >> 4, k4 = (li & 15) << 2;
    short4v o;
    #pragma unroll
    for (int j = 0; j < 4; j++) o[j] = sT[k4 + j][nr];
    const int kcol = (k0 + k4) ^ ((nr & 7) << 3);   // swz stays inside 64-block
    *reinterpret_cast<short4v*>(&OUT[(size_t)(n0 + nr) * HID + kcol]) = o;
  }
}

// ---------------- projection GEMM: z=0 Q(gated) z=1 K(gated) z=2 V ----------
__global__ __launch_bounds__(256, 2) void proj_kernel(
    const float* __restrict__ X, const short* __restrict__ WTbase,
    const float* __restrict__ bq, const float* __restrict__ bqr,
    const float* __restrict__ bk, const float* __restrict__ bkr,
    const float* __restrict__ bv, const float* __restrict__ MASK,
    __hip_bfloat16* __restrict__ qg, __hip_bfloat16* __restrict__ kg,
    __hip_bfloat16* __restrict__ vg)
{
  const int z = blockIdx.z;
  const bool gated = (z < 2);
  const short* W1T = WTbase + (size_t)(2 * z) * WT_ELEMS;  // z=2 -> slot 4
  const short* W2T = W1T + WT_ELEMS;
  const float* B1 = z == 0 ? bq : z == 1 ? bk : bv;
  const float* B2 = z == 0 ? bqr : bkr;
  __hip_bfloat16* OUT = z == 0 ? qg : z == 1 ? kg : vg;

  __shared__ short lA[128][72];     // pad 72: staging write + frag read 2-way (free)
  __shared__ short lB1[128][64];    // linear: global_load_lds dest
  __shared__ short lB2[128][64];

  const int m0 = blockIdx.x * 128, n0 = blockIdx.y * 128;
  const int tid = threadIdx.x, lane = tid & 63, w = tid >> 6;
  const int wr = (w >> 1) * 64, wc = (w & 1) * 64;
  const int lrow = lane & 15, lkhi = (lane >> 4) << 3;
  const int bswz = (lrow & 7) << 3;

  f32x4 acc1[4][4] = {}, acc2[4][4] = {};

  for (int kt = 0; kt < 16; kt++) {
    const int k0 = kt * 64;
    // A tile: fp32 -> bf16 reg staging (16B loads, 8B LDS writes, conflict-free)
    #pragma unroll
    for (int i = 0; i < 8; i++) {
      const int li = tid + i * 256;
      const int r = li >> 4, c4 = (li & 15) << 2;
      const f32x4 a4 = *reinterpret_cast<const f32x4*>(&X[(size_t)(m0 + r) * HID + k0 + c4]);
      short4v s4;
      #pragma unroll
      for (int j = 0; j < 4; j++) s4[j] = f2bs(a4[j]);
      *reinterpret_cast<short4v*>(&lA[r][c4]) = s4;
    }
    // B tiles: async global->LDS, 16B/lane, linear dest (source pre-swizzled)
    #pragma unroll
    for (int i = 0; i < 4; i++) {
      const int chunk = w * 4 + i;
      const int r = chunk * 8 + (lane >> 3), cs = (lane & 7) << 3;
      gload_lds16(&W1T[(size_t)(n0 + r) * HID + k0 + cs], &lB1[chunk * 8][0]);
    }
    if (gated) {
      #pragma unroll
      for (int i = 0; i < 4; i++) {
        const int chunk = w * 4 + i;
        const int r = chunk * 8 + (lane >> 3), cs = (lane & 7) << 3;
        gload_lds16(&W2T[(size_t)(n0 + r) * HID + k0 + cs], &lB2[chunk * 8][0]);
      }
    }
    __syncthreads();
    #pragma unroll
    for (int kk = 0; kk < 2; kk++) {
      const int lk = kk * 32 + lkhi;
      short8 af[4];
      #pragma unroll
      for (int m = 0; m < 4; m++)
        af[m] = *reinterpret_cast<const short8*>(&lA[wr + m * 16 + lrow][lk]);
      #pragma unroll
      for (int n = 0; n < 4; n++) {
        const short8 bf = *reinterpret_cast<const short8*>(&lB1[wc + n * 16 + lrow][lk ^ bswz]);
        #pragma unroll
        for (int m = 0; m < 4; m++)
          acc1[m][n] = __builtin_amdgcn_mfma_f32_16x16x32_bf16(af[m], bf, acc1[m][n], 0, 0, 0);
      }
      if (gated) {
        #pragma unroll
        for (int n = 0; n < 4; n++) {
          const short8 bf = *reinterpret_cast<const short8*>(&lB2[wc + n * 16 + lrow][lk ^ bswz]);
          #pragma unroll
          for (int m = 0; m < 4; m++)
            acc2[m][n] = __builtin_amdgcn_mfma_f32_16x16x32_bf16(af[m], bf, acc2[m][n], 0, 0, 0);
        }
      }
    }
    __syncthreads();
  }

  // epilogue: bias + reasoning-mask blend; C/D: col=lane&15, row=(lane>>4)*4+r
  #pragma unroll
  for (int m = 0; m < 4; m++) {
    const int rbase = m0 + wr + m * 16 + ((lane >> 4) << 2);
    #pragma unroll
    for (int n = 0; n < 4; n++) {
      const int col = n0 + wc + n * 16 + lrow;
      const float bias1 = B1[col];
      float bias2 = 0.f;
      if (gated) bias2 = B2[col];
      #pragma unroll
      for (int r = 0; r < 4; r++) {
        const int row = rbase + r;
        float val = acc1[m][n][r] + bias1;
        if (gated) {
          const float mk = MASK[row];
          val = val * (1.f - mk) + (acc2[m][n][r] + bias2) * mk;
        }
        OUT[(size_t)row * HID + col] = __float2bfloat16(val);
      }
    }
  }
}

// ---------------- per-token 16x16 cross-head attention ----------------------
// out row = b*2048 + h*128 + s/16, col = (s%16)*64 + d, stored with the same
// 64-block swizzle (d ^= (row&7)<<3) so out_gemm can global_load_lds it.
__global__ __launch_bounds__(256) void attn_kernel(
    const __hip_bfloat16* __restrict__ Q, const __hip_bfloat16* __restrict__ K,
    const __hip_bfloat16* __restrict__ V, __hip_bfloat16* __restrict__ O)
{
  const int t = blockIdx.x;
  const int b = t >> 11, s = t & 2047;
  __shared__ float sQ[16][68], sK[16][68], sV[16][68];
  __shared__ float sA[16][17];
  const int tid = threadIdx.x;
  const size_t tb = (size_t)t * HID;

  {
    const int h = tid >> 4, d0 = (tid & 15) << 2;
    const int o = (h << 6) + d0;
    const short4v qv = *reinterpret_cast<const short4v*>(&((const short*)Q)[tb + o]);
    const short4v kv = *reinterpret_cast<const short4v*>(&((const short*)K)[tb + o]);
    const short4v vv = *reinterpret_cast<const short4v*>(&((const short*)V)[tb + o]);
    #pragma unroll
    for (int j = 0; j < 4; j++) {
      sQ[h][d0 + j] = bs2f(qv[j]);
      sK[h][d0 + j] = bs2f(kv[j]);
      sV[h][d0 + j] = bs2f(vv[j]);
    }
  }
  __syncthreads();

  const int h = tid >> 4, e = tid & 15;
  float sc = 0.f;
  #pragma unroll
  for (int d = 0; d < 64; d++) sc += sQ[h][d] * sK[e][d];
  sc *= 0.125f;

  float mx = sc;
  mx = fmaxf(mx, __shfl_xor(mx, 1));
  mx = fmaxf(mx, __shfl_xor(mx, 2));
  mx = fmaxf(mx, __shfl_xor(mx, 4));
  mx = fmaxf(mx, __shfl_xor(mx, 8));
  const float p = __expf(sc - mx);
  float sm = p;
  sm += __shfl_xor(sm, 1);
  sm += __shfl_xor(sm, 2);
  sm += __shfl_xor(sm, 4);
  sm += __shfl_xor(sm, 8);
  sA[h][e] = p / sm;
  __syncthreads();

  const int row7 = (s >> 4) & 7;
  const size_t ob = ((size_t)b * 2048 + (s >> 4)) * HID + ((size_t)(s & 15) << 6);
  {
    const int hh = tid >> 4, d4 = (tid & 15) << 2;
    f32x4 o = {0.f, 0.f, 0.f, 0.f};
    #pragma unroll
    for (int e2 = 0; e2 < 16; e2++) {
      const float a = sA[hh][e2];
      #pragma unroll
      for (int j = 0; j < 4; j++) o[j] += a * sV[e2][d4 + j];
    }
    short4v ov;
    #pragma unroll
    for (int j = 0; j < 4; j++) ov[j] = f2bs(o[j]);
    *reinterpret_cast<short4v*>(
        &((short*)O)[ob + (size_t)hh * 128 * HID + (d4 ^ (row7 << 3))]) = ov;
  }
}

// ---------------- final GEMM: ar @ WoT + bo -> fp32 -------------------------
__global__ __launch_bounds__(256) void out_gemm_kernel(
    const short* __restrict__ A, const short* __restrict__ WT,
    const float* __restrict__ BIAS, float* __restrict__ OUT)
{
  __shared__ short lA[128][64];
  __shared__ short lB[128][64];
  const int m0 = blockIdx.x * 128, n0 = blockIdx.y * 128;
  const int tid = threadIdx.x, lane = tid & 63, w = tid >> 6;
  const int wr = (w >> 1) * 64, wc = (w & 1) * 64;
  const int lrow = lane & 15, lkhi = (lane >> 4) << 3;
  const int bswz = (lrow & 7) << 3;

  f32x4 acc[4][4] = {};

  for (int kt = 0; kt < 16; kt++) {
    const int k0 = kt * 64;
    #pragma unroll
    for (int i = 0; i < 4; i++) {
      const int chunk = w * 4 + i;
      const int r = chunk * 8 + (lane >> 3), cs = (lane & 7) << 3;
      gload_lds16(&A[(size_t)(m0 + r) * HID + k0 + cs], &lA[chunk * 8][0]);
      gload_lds16(&WT[(size_t)(n0 + r) * HID + k0 + cs], &lB[chunk * 8][0]);
    }
    __syncthreads();
    #pragma unroll
    for (int kk = 0; kk < 2; kk++) {
      const int lk = kk * 32 + lkhi;
      short8 af[4];
      #pragma unroll
      for (int m = 0; m < 4; m++)
        af[m] = *reinterpret_cast<const short8*>(&lA[wr + m * 16 + lrow][lk ^ bswz]);
      #pragma unroll
      for (int n = 0; n < 4; n++) {
        const short8 bf = *reinterpret_cast<const short8*>(&lB[wc + n * 16 + lrow][lk ^ bswz]);
        #pragma unroll
        for (int m = 0; m < 4; m++)
          acc[m][n] = __builtin_amdgcn_mfma_f32_16x16x32_bf16(af[m], bf, acc[m][n], 0, 0, 0);
      }
    }
    __syncthreads();
  }

  #pragma unroll
  for (int m = 0; m < 4; m++) {
    const int rbase = m0 + wr + m * 16 + ((lane >> 4) << 2);
    #pragma unroll
    for (int n = 0; n < 4; n++) {
      const int col = n0 + wc + n * 16 + lrow;
      const float bias = BIAS[col];
      #pragma unroll
      for (int r = 0; r < 4; r++)
        OUT[(size_t)(rbase + r) * HID + col] = acc[m][n][r] + bias;
    }
  }
}

extern "C" void kernel_launch(void* const* d_in, const int* in_sizes, int n_in,
                              void* d_out, int out_size, void* d_ws, size_t ws_size,
                              hipStream_t stream) {
  (void)in_sizes; (void)n_in; (void)out_size; (void)ws_size;
  const float* x   = (const float*)d_in[0];
  const float* rm  = (const float*)d_in[1];
  const float* Wq  = (const float*)d_in[2];
  const float* bq  = (const float*)d_in[3];
  const float* Wk  = (const float*)d_in[4];
  const float* bk  = (const float*)d_in[5];
  const float* Wv  = (const float*)d_in[6];
  const float* bv  = (const float*)d_in[7];
  const float* Wqr = (const float*)d_in[8];
  const float* bqr = (const float*)d_in[9];
  const float* Wkr = (const float*)d_in[10];
  const float* bkr = (const float*)d_in[11];
  const float* Wo  = (const float*)d_in[12];
  const float* bo  = (const float*)d_in[13];

  // ws layout (67.1 MB, same as round 2):
  short* wt5 = (short*)d_ws;                                  // 5x2MB, dies after proj
  __hip_bfloat16* ar = (__hip_bfloat16*)d_ws;                 // overwrites wt5 at attn
  __hip_bfloat16* qg = (__hip_bfloat16*)d_ws + P_ELEMS;
  __hip_bfloat16* kg = qg + P_ELEMS;
  __hip_bfloat16* vv = kg + P_ELEMS;
  short* wot = (short*)qg;                                    // overwrites qg after attn

  // WT order: [WqT][WqrT][WkT][WkrT][WvT]
  transpose_kernel<<<dim3(16, 16, 5), 256, 0, stream>>>(Wq, Wqr, Wk, Wkr, Wv, wt5);
  proj_kernel<<<dim3(64, 8, 3), 256, 0, stream>>>(x, wt5, bq, bqr, bk, bkr, bv, rm,
                                                  qg, kg, vv);
  attn_kernel<<<dim3(NTOK), 256, 0, stream>>>(qg, kg, vv, ar);
  transpose_kernel<<<dim3(16, 16, 1), 256, 0, stream>>>(Wo, Wo, Wo, Wo, Wo, wot);
  out_gemm_kernel<<<dim3(64, 8), 256, 0, stream>>>((const short*)ar, wot, bo,
                                                   (float*)d_out);
}

// Round 4
// 167.589 us; speedup vs baseline: 3.8116x; 1.0643x over previous
//
#include <hip/hip_runtime.h>
#include <hip/hip_bf16.h>

// ReasoningMultiHeadAttention: B=4 S=2048 HID=1024 NH=16 DH=64. All I/O fp32.
// prep: 6x W -> bf16 W^T pre-swizzled (wt, ws) ; x -> bf16 xb pre-swizzled (in d_out!)
// gated8: 8-phase counted-vmcnt GEMM, dual-B: qg (ws), kg (in d_out hi half!)
// plain8<bf16>: xb @ WvT + bv -> vv (ws)
// attn: per-token 16x16 cross-head attn -> ar (ws, swizzled+scrambled)
// plain8<f32>: ar @ WoT + bo -> d_out (overwrites xb/kg scratch, all dead)
// ws usage: [0:12M wt][12:28M qg][28:44M vv][44:60M ar] = 60 MB
// d_out scratch: [0:16M xb][16:32M kg] until final GEMM rewrites all of d_out.

typedef __attribute__((ext_vector_type(8))) short short8;
typedef __attribute__((ext_vector_type(4))) short short4v;
typedef __attribute__((ext_vector_type(4))) float f32x4;

#define HID 1024
#define NTOK 8192
#define WT_ELEMS (1024 * 1024)

__device__ __forceinline__ short f2bs(float f) {
  __hip_bfloat16 h = __float2bfloat16(f);
  return *reinterpret_cast<short*>(&h);
}
__device__ __forceinline__ float bs2f(short s) {
  __hip_bfloat16 h;
  *reinterpret_cast<short*>(&h) = s;
  return __bfloat162float(h);
}
__device__ __forceinline__ void gload16(const void* g, void* l) {
  __builtin_amdgcn_global_load_lds(
      (const __attribute__((address_space(1))) void*)g,
      (__attribute__((address_space(3))) void*)l, 16, 0, 0);
}

#define BAR() asm volatile("s_barrier" ::: "memory")
#define VMWAIT(N) asm volatile("s_waitcnt vmcnt(" #N ")" ::: "memory")
#define PRIO1 __builtin_amdgcn_s_setprio(1)
#define PRIO0 __builtin_amdgcn_s_setprio(0)

// ---------------- prep: W transposes (z<6) + x fp32->bf16 convert ----------
// WT[n][ (k&~63) | ((k&63) ^ ((n&7)<<3)) ] = bf16(W[k][n])
// XB[row][ (k&~63) | ((k&63) ^ ((row&7)<<3)) ] = bf16(x[row][k])
__global__ __launch_bounds__(256) void prep_kernel(
    const float* __restrict__ W0, const float* __restrict__ W1,
    const float* __restrict__ W2, const float* __restrict__ W3,
    const float* __restrict__ W4, const float* __restrict__ W5,
    const float* __restrict__ X, short* __restrict__ WT, short* __restrict__ XB)
{
  __shared__ short sT[64][68];
  const int bid = blockIdx.x, tid = threadIdx.x;
  if (bid < 1536) {
    const int z = bid >> 8, rem = bid & 255;
    const float* W = z == 0 ? W0 : z == 1 ? W1 : z == 2 ? W2 : z == 3 ? W3
                   : z == 4 ? W4 : W5;
    short* OUT = WT + (size_t)z * WT_ELEMS;
    const int k0 = (rem & 15) * 64, n0 = (rem >> 4) * 64;
    #pragma unroll
    for (int i = 0; i < 4; i++) {
      const int li = tid + i * 256;
      const int kr = li >> 4, c4 = (li & 15) << 2;
      const f32x4 wv = *reinterpret_cast<const f32x4*>(&W[(size_t)(k0 + kr) * HID + n0 + c4]);
      short4v s4;
      #pragma unroll
      for (int j = 0; j < 4; j++) s4[j] = f2bs(wv[j]);
      *reinterpret_cast<short4v*>(&sT[kr][c4]) = s4;
    }
    __syncthreads();
    #pragma unroll
    for (int i = 0; i < 4; i++) {
      const int li = tid + i * 256;
      const int nr = li >> 4, k4 = (li & 15) << 2;
      short4v o;
      #pragma unroll
      for (int j = 0; j < 4; j++) o[j] = sT[k4 + j][nr];
      const int kcol = (k0 + k4) ^ ((nr & 7) << 3);
      *reinterpret_cast<short4v*>(&OUT[(size_t)(n0 + nr) * HID + kcol]) = o;
    }
  } else {
    const int gid = (bid - 1536) * 256 + tid;      // 0..1048575
    const int row = gid >> 7, kc = (gid & 127) << 3;
    const f32x4 a = *reinterpret_cast<const f32x4*>(&X[(size_t)row * HID + kc]);
    const f32x4 b = *reinterpret_cast<const f32x4*>(&X[(size_t)row * HID + kc + 4]);
    short8 s;
    #pragma unroll
    for (int j = 0; j < 4; j++) { s[j] = f2bs(a[j]); s[4 + j] = f2bs(b[j]); }
    const int phys = (kc & ~63) | ((kc & 63) ^ ((row & 7) << 3));
    *reinterpret_cast<short8*>(&XB[(size_t)row * HID + phys]) = s;
  }
}

// ---------------- gated 8-phase GEMM: z=0 -> qg, z=1 -> kg ------------------
// BM=256 BN=128 BK=64, 512 thr (8 waves, 4M x 2N), dual-B, counted vmcnt(2).
__global__ __launch_bounds__(512, 2) void gated8_kernel(
    const short* __restrict__ XB, const short* __restrict__ WTbase,
    const float* __restrict__ bq, const float* __restrict__ bqr,
    const float* __restrict__ bk, const float* __restrict__ bkr,
    const float* __restrict__ MASK,
    __hip_bfloat16* __restrict__ qg, __hip_bfloat16* __restrict__ kg)
{
  __shared__ short lA[2][256][64];    // 64 KB
  __shared__ short lB1[2][128][64];   // 32 KB
  __shared__ short lB2[2][128][64];   // 32 KB

  const int z = blockIdx.z;
  const short* W1T = WTbase + (size_t)(2 * z) * WT_ELEMS;
  const short* W2T = W1T + WT_ELEMS;
  const float* B1b = z ? bk : bq;
  const float* B2b = z ? bkr : bqr;
  __hip_bfloat16* OUT = z ? kg : qg;

  const int m0 = blockIdx.x * 256, n0 = blockIdx.y * 128;
  const int tid = threadIdx.x, lane = tid & 63, w = tid >> 6;
  const int wr = (w >> 1) * 64, wc = (w & 1) * 64;
  const int lrow = lane & 15, lkhi = (lane >> 4) << 3;
  const int swz = (lrow & 7) << 3;
  const int srow = lane >> 3, scol = (lane & 7) << 3;

  f32x4 acc1[4][4] = {}, acc2[4][4] = {};
  short8 bf1k[4], bf2k[4], af0, af1;

  auto stA2 = [&](int slot, int kt, int i0) {   // 2 A-issues
    const int k0 = kt * 64;
    #pragma unroll
    for (int i = 0; i < 2; i++) {
      const int chunk = w * 4 + i0 + i;
      gload16(&XB[(size_t)(m0 + chunk * 8 + srow) * HID + k0 + scol],
              &lA[slot][chunk * 8][0]);
    }
  };
  auto stB1s = [&](int slot, int kt) {          // 2 B1-issues
    const int k0 = kt * 64;
    #pragma unroll
    for (int i = 0; i < 2; i++) {
      const int chunk = w * 2 + i;
      gload16(&W1T[(size_t)(n0 + chunk * 8 + srow) * HID + k0 + scol],
              &lB1[slot][chunk * 8][0]);
    }
  };
  auto stB2s = [&](int slot, int kt) {          // 2 B2-issues
    const int k0 = kt * 64;
    #pragma unroll
    for (int i = 0; i < 2; i++) {
      const int chunk = w * 2 + i;
      gload16(&W2T[(size_t)(n0 + chunk * 8 + srow) * HID + k0 + scol],
              &lB2[slot][chunk * 8][0]);
    }
  };
  auto rdA = [&](int s, int m, int kk) -> short8 {
    const int lk = (kk * 32 + lkhi) ^ swz;
    return *reinterpret_cast<const short8*>(&lA[s][wr + m * 16 + lrow][lk]);
  };
  auto rdB1 = [&](int s, int n, int kk) -> short8 {
    const int lk = (kk * 32 + lkhi) ^ swz;
    return *reinterpret_cast<const short8*>(&lB1[s][wc + n * 16 + lrow][lk]);
  };
  auto rdB2 = [&](int s, int n, int kk) -> short8 {
    const int lk = (kk * 32 + lkhi) ^ swz;
    return *reinterpret_cast<const short8*>(&lB2[s][wc + n * 16 + lrow][lk]);
  };

#define RDBF(S, KK)                               \
  _Pragma("unroll")                               \
  for (int n = 0; n < 4; n++) {                   \
    bf1k[n] = rdB1(S, n, KK);                     \
    bf2k[n] = rdB2(S, n, KK);                     \
  }
#define MM16(MB)                                                                          \
  _Pragma("unroll")                                                                       \
  for (int n = 0; n < 4; n++) {                                                           \
    acc1[MB][n]     = __builtin_amdgcn_mfma_f32_16x16x32_bf16(af0, bf1k[n], acc1[MB][n], 0, 0, 0);     \
    acc1[MB + 1][n] = __builtin_amdgcn_mfma_f32_16x16x32_bf16(af1, bf1k[n], acc1[MB + 1][n], 0, 0, 0); \
    acc2[MB][n]     = __builtin_amdgcn_mfma_f32_16x16x32_bf16(af0, bf2k[n], acc2[MB][n], 0, 0, 0);     \
    acc2[MB + 1][n] = __builtin_amdgcn_mfma_f32_16x16x32_bf16(af1, bf2k[n], acc2[MB + 1][n], 0, 0, 0); \
  }
// Half-iteration: compute tile in slot S (full K=64), stage tile TS into slot SN.
// Phases: P1: af(m01,kk0)+bf(kk0) | P2: af(m23,kk0) | P3: af(m01,kk1)+bf(kk1) | P4: af(m23,kk1)
#define GHALF(S, SN, TS)                                    \
  stA2(SN, TS, 0);                                          \
  VMWAIT(2);                                                \
  BAR();                                                    \
  af0 = rdA(S, 0, 0); af1 = rdA(S, 1, 0); RDBF(S, 0);       \
  PRIO1; MM16(0); PRIO0;                                    \
  BAR();                                                    \
  af0 = rdA(S, 2, 0); af1 = rdA(S, 3, 0);                   \
  stA2(SN, TS, 2);                                          \
  BAR();                                                    \
  PRIO1; MM16(2); PRIO0;                                    \
  BAR();                                                    \
  af0 = rdA(S, 0, 1); af1 = rdA(S, 1, 1); RDBF(S, 1);       \
  stB1s(SN, TS);                                            \
  BAR();                                                    \
  PRIO1; MM16(0); PRIO0;                                    \
  BAR();                                                    \
  af0 = rdA(S, 2, 1); af1 = rdA(S, 3, 1);                   \
  stB2s(SN, TS);                                            \
  BAR();                                                    \
  PRIO1; MM16(2); PRIO0;                                    \
  BAR();

  // prologue: stage tile 0 into slot 0 (8 issues)
  stA2(0, 0, 0); stA2(0, 0, 2); stB1s(0, 0); stB2s(0, 0);

  #pragma unroll 1
  for (int i = 0; i < 8; i++) {
    const int tb = 2 * i + 1;
    const int tn = (i < 7) ? 2 * i + 2 : 15;   // last iter: harmless restage
    GHALF(0, 1, tb)    // compute tile 2i   (slot0), stage tile 2i+1 -> slot1
    GHALF(1, 0, tn)    // compute tile 2i+1 (slot1), stage tile 2i+2 -> slot0
  }
  VMWAIT(0);
#undef GHALF
#undef MM16
#undef RDBF

  // epilogue: bias + reasoning-mask blend; C/D: col=lane&15, row=(lane>>4)*4+r
  #pragma unroll
  for (int m = 0; m < 4; m++) {
    const int rbase = m0 + wr + m * 16 + ((lane >> 4) << 2);
    #pragma unroll
    for (int n = 0; n < 4; n++) {
      const int col = n0 + wc + n * 16 + lrow;
      const float bias1 = B1b[col];
      const float bias2 = B2b[col];
      #pragma unroll
      for (int r = 0; r < 4; r++) {
        const int row = rbase + r;
        const float mk = MASK[row];
        const float val = (acc1[m][n][r] + bias1) * (1.f - mk) +
                          (acc2[m][n][r] + bias2) * mk;
        OUT[(size_t)row * HID + col] = __float2bfloat16(val);
      }
    }
  }
}

// ---------------- plain 8-phase GEMM (single B): V-proj and out-proj --------
// BM=256 BN=128 BK=64, 512 thr, counted vmcnt(3), 2 phases per K-tile.
template<bool OUTF32>
__global__ __launch_bounds__(512, 2) void plain8_kernel(
    const short* __restrict__ A, const short* __restrict__ WT,
    const float* __restrict__ BIAS, void* __restrict__ OUTv)
{
  __shared__ short lA[2][256][64];    // 64 KB
  __shared__ short lB[2][128][64];    // 32 KB

  const int m0 = blockIdx.x * 256, n0 = blockIdx.y * 128;
  const int tid = threadIdx.x, lane = tid & 63, w = tid >> 6;
  const int wr = (w >> 1) * 64, wc = (w & 1) * 64;
  const int lrow = lane & 15, lkhi = (lane >> 4) << 3;
  const int swz = (lrow & 7) << 3;
  const int srow = lane >> 3, scol = (lane & 7) << 3;

  f32x4 acc[4][4] = {};
  short8 paf[4], pbf[4];

  auto stTrip = [&](int slot, int kt, int t) {  // 3 issues: t=0 -> A{0,1,2}; t=1 -> A3,B0,B1
    const int k0 = kt * 64;
    if (t == 0) {
      #pragma unroll
      for (int i = 0; i < 3; i++) {
        const int chunk = w * 4 + i;
        gload16(&A[(size_t)(m0 + chunk * 8 + srow) * HID + k0 + scol],
                &lA[slot][chunk * 8][0]);
      }
    } else {
      const int chunk = w * 4 + 3;
      gload16(&A[(size_t)(m0 + chunk * 8 + srow) * HID + k0 + scol],
              &lA[slot][chunk * 8][0]);
      #pragma unroll
      for (int i = 0; i < 2; i++) {
        const int bchunk = w * 2 + i;
        gload16(&WT[(size_t)(n0 + bchunk * 8 + srow) * HID + k0 + scol],
                &lB[slot][bchunk * 8][0]);
      }
    }
  };

#define RDP(S, KK)                                                                  \
  _Pragma("unroll")                                                                 \
  for (int m = 0; m < 4; m++) {                                                     \
    const int lk = ((KK) * 32 + lkhi) ^ swz;                                        \
    paf[m] = *reinterpret_cast<const short8*>(&lA[S][wr + m * 16 + lrow][lk]);      \
    pbf[m] = *reinterpret_cast<const short8*>(&lB[S][wc + m * 16 + lrow][lk]);      \
  }
#define PMM16                                                                       \
  _Pragma("unroll")                                                                 \
  for (int m = 0; m < 4; m++)                                                       \
    _Pragma("unroll")                                                               \
    for (int n = 0; n < 4; n++)                                                     \
      acc[m][n] = __builtin_amdgcn_mfma_f32_16x16x32_bf16(paf[m], pbf[n], acc[m][n], 0, 0, 0);
// Half-iteration: compute slot S over kk0,kk1; stage tile TS into slot SN (2 trips).
#define PHALF(S, SN, TS)        \
  stTrip(SN, TS, 0);            \
  VMWAIT(3);                    \
  BAR();                        \
  RDP(S, 0)                     \
  PRIO1; PMM16 PRIO0;           \
  BAR();                        \
  RDP(S, 1)                     \
  stTrip(SN, TS, 1);            \
  BAR();                        \
  PRIO1; PMM16 PRIO0;           \
  BAR();

  stTrip(0, 0, 0); stTrip(0, 0, 1);   // prologue: tile 0 -> slot 0 (6 issues)

  #pragma unroll 1
  for (int i = 0; i < 8; i++) {
    const int tb = 2 * i + 1;
    const int tn = (i < 7) ? 2 * i + 2 : 15;
    PHALF(0, 1, tb)
    PHALF(1, 0, tn)
  }
  VMWAIT(0);
#undef PHALF
#undef PMM16
#undef RDP

  #pragma unroll
  for (int m = 0; m < 4; m++) {
    const int rbase = m0 + wr + m * 16 + ((lane >> 4) << 2);
    #pragma unroll
    for (int n = 0; n < 4; n++) {
      const int col = n0 + wc + n * 16 + lrow;
      const float bias = BIAS[col];
      #pragma unroll
      for (int r = 0; r < 4; r++) {
        const float val = acc[m][n][r] + bias;
        const size_t oidx = (size_t)(rbase + r) * HID + col;
        if (OUTF32) ((float*)OUTv)[oidx] = val;
        else ((__hip_bfloat16*)OUTv)[oidx] = __float2bfloat16(val);
      }
    }
  }
}

// ---------------- per-token 16x16 cross-head attention ----------------------
// out row = b*2048 + h*128 + s/16, col = (s%16)*64 + d, stored with the
// 64-block swizzle (d ^= (row&7)<<3) so the final GEMM can global_load_lds it.
__global__ __launch_bounds__(256) void attn_kernel(
    const __hip_bfloat16* __restrict__ Q, const __hip_bfloat16* __restrict__ K,
    const __hip_bfloat16* __restrict__ V, __hip_bfloat16* __restrict__ O)
{
  const int t = blockIdx.x;
  const int b = t >> 11, s = t & 2047;
  __shared__ float sQ[16][68], sK[16][68], sV[16][68];
  __shared__ float sA[16][17];
  const int tid = threadIdx.x;
  const size_t tb = (size_t)t * HID;

  {
    const int h = tid >> 4, d0 = (tid & 15) << 2;
    const int o = (h << 6) + d0;
    const short4v qv = *reinterpret_cast<const short4v*>(&((const short*)Q)[tb + o]);
    const short4v kv = *reinterpret_cast<const short4v*>(&((const short*)K)[tb + o]);
    const short4v vv = *reinterpret_cast<const short4v*>(&((const short*)V)[tb + o]);
    #pragma unroll
    for (int j = 0; j < 4; j++) {
      sQ[h][d0 + j] = bs2f(qv[j]);
      sK[h][d0 + j] = bs2f(kv[j]);
      sV[h][d0 + j] = bs2f(vv[j]);
    }
  }
  __syncthreads();

  const int h = tid >> 4, e = tid & 15;
  float sc = 0.f;
  #pragma unroll
  for (int d = 0; d < 64; d++) sc += sQ[h][d] * sK[e][d];
  sc *= 0.125f;

  float mx = sc;
  mx = fmaxf(mx, __shfl_xor(mx, 1));
  mx = fmaxf(mx, __shfl_xor(mx, 2));
  mx = fmaxf(mx, __shfl_xor(mx, 4));
  mx = fmaxf(mx, __shfl_xor(mx, 8));
  const float p = __expf(sc - mx);
  float sm = p;
  sm += __shfl_xor(sm, 1);
  sm += __shfl_xor(sm, 2);
  sm += __shfl_xor(sm, 4);
  sm += __shfl_xor(sm, 8);
  sA[h][e] = p / sm;
  __syncthreads();

  const int row7 = (s >> 4) & 7;
  const size_t ob = ((size_t)b * 2048 + (s >> 4)) * HID + ((size_t)(s & 15) << 6);
  {
    const int hh = tid >> 4, d4 = (tid & 15) << 2;
    f32x4 o = {0.f, 0.f, 0.f, 0.f};
    #pragma unroll
    for (int e2 = 0; e2 < 16; e2++) {
      const float a = sA[hh][e2];
      #pragma unroll
      for (int j = 0; j < 4; j++) o[j] += a * sV[e2][d4 + j];
    }
    short4v ov;
    #pragma unroll
    for (int j = 0; j < 4; j++) ov[j] = f2bs(o[j]);
    *reinterpret_cast<short4v*>(
        &((short*)O)[ob + (size_t)hh * 128 * HID + (d4 ^ (row7 << 3))]) = ov;
  }
}

extern "C" void kernel_launch(void* const* d_in, const int* in_sizes, int n_in,
                              void* d_out, int out_size, void* d_ws, size_t ws_size,
                              hipStream_t stream) {
  (void)in_sizes; (void)n_in; (void)out_size; (void)ws_size;
  const float* x   = (const float*)d_in[0];
  const float* rm  = (const float*)d_in[1];
  const float* Wq  = (const float*)d_in[2];
  const float* bq  = (const float*)d_in[3];
  const float* Wk  = (const float*)d_in[4];
  const float* bk  = (const float*)d_in[5];
  const float* Wv  = (const float*)d_in[6];
  const float* bv  = (const float*)d_in[7];
  const float* Wqr = (const float*)d_in[8];
  const float* bqr = (const float*)d_in[9];
  const float* Wkr = (const float*)d_in[10];
  const float* bkr = (const float*)d_in[11];
  const float* Wo  = (const float*)d_in[12];
  const float* bo  = (const float*)d_in[13];

  // ws: [0:12M) WT (Wq,Wqr,Wk,Wkr,Wv,Wo) | [12:28M) qg | [28:44M) vv | [44:60M) ar
  char* ws = (char*)d_ws;
  short* wt = (short*)ws;
  __hip_bfloat16* qg = (__hip_bfloat16*)(ws + 12u * 1024 * 1024);
  __hip_bfloat16* vv = (__hip_bfloat16*)(ws + 28u * 1024 * 1024);
  __hip_bfloat16* ar = (__hip_bfloat16*)(ws + 44u * 1024 * 1024);
  // d_out (32 MiB fp32) doubles as scratch until the final GEMM rewrites it:
  short* xb = (short*)d_out;                                        // [0:16M)
  __hip_bfloat16* kg = (__hip_bfloat16*)((char*)d_out + 16u * 1024 * 1024);  // [16:32M)

  prep_kernel<<<dim3(5632), 256, 0, stream>>>(Wq, Wqr, Wk, Wkr, Wv, Wo, x, wt, xb);
  gated8_kernel<<<dim3(32, 8, 2), 512, 0, stream>>>(xb, wt, bq, bqr, bk, bkr, rm, qg, kg);
  plain8_kernel<false><<<dim3(32, 8), 512, 0, stream>>>(xb, wt + (size_t)4 * WT_ELEMS, bv, vv);
  attn_kernel<<<dim3(NTOK), 256, 0, stream>>>(qg, kg, vv, ar);
  plain8_kernel<true><<<dim3(32, 8), 512, 0, stream>>>((const short*)ar,
                                                       wt + (size_t)5 * WT_ELEMS, bo, d_out);
}

// Round 5
// 165.675 us; speedup vs baseline: 3.8557x; 1.0116x over previous
//
#include <hip/hip_runtime.h>
#include <hip/hip_bf16.h>

// ReasoningMultiHeadAttention: B=4 S=2048 HID=1024 NH=16 DH=64. All I/O fp32.
// prep: 6x W -> bf16 W^T pre-swizzled (wt, ws) ; x -> bf16 xb pre-swizzled (in d_out!)
// gated8: 8-phase counted-vmcnt GEMM with READ-AHEAD, dual-B: qg (ws), kg (d_out hi)
// plain8<bf16>: xb @ WvT + bv -> vv (ws)
// attn: per-token 16x16 cross-head attn -> ar (ws, swizzled+scrambled)
// plain8<f32>: ar @ WoT + bo -> d_out (overwrites xb/kg scratch, all dead)
// ws usage: [0:12M wt][12:28M qg][28:44M vv][44:60M ar] = 60 MB
// d_out scratch: [0:16M xb][16:32M kg] until final GEMM rewrites all of d_out.

typedef __attribute__((ext_vector_type(8))) short short8;
typedef __attribute__((ext_vector_type(4))) short short4v;
typedef __attribute__((ext_vector_type(4))) float f32x4;

#define HID 1024
#define NTOK 8192
#define WT_ELEMS (1024 * 1024)

__device__ __forceinline__ short f2bs(float f) {
  __hip_bfloat16 h = __float2bfloat16(f);
  return *reinterpret_cast<short*>(&h);
}
__device__ __forceinline__ float bs2f(short s) {
  __hip_bfloat16 h;
  *reinterpret_cast<short*>(&h) = s;
  return __bfloat162float(h);
}
__device__ __forceinline__ void gload16(const void* g, void* l) {
  __builtin_amdgcn_global_load_lds(
      (const __attribute__((address_space(1))) void*)g,
      (__attribute__((address_space(3))) void*)l, 16, 0, 0);
}

#define BAR() asm volatile("s_barrier" ::: "memory")
#define VMWAIT(N) asm volatile("s_waitcnt vmcnt(" #N ")" ::: "memory")
#define PRIO1 __builtin_amdgcn_s_setprio(1)
#define PRIO0 __builtin_amdgcn_s_setprio(0)

// ---------------- prep: W transposes (z<6) + x fp32->bf16 convert ----------
// WT[n][ (k&~63) | ((k&63) ^ ((n&7)<<3)) ] = bf16(W[k][n])
// XB[row][ (k&~63) | ((k&63) ^ ((row&7)<<3)) ] = bf16(x[row][k])
__global__ __launch_bounds__(256) void prep_kernel(
    const float* __restrict__ W0, const float* __restrict__ W1,
    const float* __restrict__ W2, const float* __restrict__ W3,
    const float* __restrict__ W4, const float* __restrict__ W5,
    const float* __restrict__ X, short* __restrict__ WT, short* __restrict__ XB)
{
  __shared__ short sT[64][68];
  const int bid = blockIdx.x, tid = threadIdx.x;
  if (bid < 1536) {
    const int z = bid >> 8, rem = bid & 255;
    const float* W = z == 0 ? W0 : z == 1 ? W1 : z == 2 ? W2 : z == 3 ? W3
                   : z == 4 ? W4 : W5;
    short* OUT = WT + (size_t)z * WT_ELEMS;
    const int k0 = (rem & 15) * 64, n0 = (rem >> 4) * 64;
    #pragma unroll
    for (int i = 0; i < 4; i++) {
      const int li = tid + i * 256;
      const int kr = li >> 4, c4 = (li & 15) << 2;
      const f32x4 wv = *reinterpret_cast<const f32x4*>(&W[(size_t)(k0 + kr) * HID + n0 + c4]);
      short4v s4;
      #pragma unroll
      for (int j = 0; j < 4; j++) s4[j] = f2bs(wv[j]);
      *reinterpret_cast<short4v*>(&sT[kr][c4]) = s4;
    }
    __syncthreads();
    #pragma unroll
    for (int i = 0; i < 4; i++) {
      const int li = tid + i * 256;
      const int nr = li >> 4, k4 = (li & 15) << 2;
      short4v o;
      #pragma unroll
      for (int j = 0; j < 4; j++) o[j] = sT[k4 + j][nr];
      const int kcol = (k0 + k4) ^ ((nr & 7) << 3);
      *reinterpret_cast<short4v*>(&OUT[(size_t)(n0 + nr) * HID + kcol]) = o;
    }
  } else {
    const int gid = (bid - 1536) * 256 + tid;      // 0..1048575
    const int row = gid >> 7, kc = (gid & 127) << 3;
    const f32x4 a = *reinterpret_cast<const f32x4*>(&X[(size_t)row * HID + kc]);
    const f32x4 b = *reinterpret_cast<const f32x4*>(&X[(size_t)row * HID + kc + 4]);
    short8 s;
    #pragma unroll
    for (int j = 0; j < 4; j++) { s[j] = f2bs(a[j]); s[4 + j] = f2bs(b[j]); }
    const int phys = (kc & ~63) | ((kc & 63) ^ ((row & 7) << 3));
    *reinterpret_cast<short8*>(&XB[(size_t)row * HID + phys]) = s;
  }
}

// ---------------- gated 8-phase GEMM: z=0 -> qg, z=1 -> kg ------------------
// BM=256 BN=128 BK=64, 512 thr (8 waves, 4M x 2N), dual-B, counted vmcnt(2),
// READ-AHEAD: each quadrant's ds_reads issued one barrier-phase early.
__global__ __launch_bounds__(512, 2) void gated8_kernel(
    const short* __restrict__ XB, const short* __restrict__ WTbase,
    const float* __restrict__ bq, const float* __restrict__ bqr,
    const float* __restrict__ bk, const float* __restrict__ bkr,
    const float* __restrict__ MASK,
    __hip_bfloat16* __restrict__ qg, __hip_bfloat16* __restrict__ kg)
{
  __shared__ short lA[2][256][64];    // 64 KB
  __shared__ short lB1[2][128][64];   // 32 KB
  __shared__ short lB2[2][128][64];   // 32 KB

  const int z = blockIdx.z;
  const short* W1T = WTbase + (size_t)(2 * z) * WT_ELEMS;
  const short* W2T = W1T + WT_ELEMS;
  const float* B1b = z ? bk : bq;
  const float* B2b = z ? bkr : bqr;
  __hip_bfloat16* OUT = z ? kg : qg;

  const int m0 = blockIdx.x * 256, n0 = blockIdx.y * 128;
  const int tid = threadIdx.x, lane = tid & 63, w = tid >> 6;
  const int wr = (w >> 1) * 64, wc = (w & 1) * 64;
  const int lrow = lane & 15, lkhi = (lane >> 4) << 3;
  const int swz = (lrow & 7) << 3;
  const int srow = lane >> 3, scol = (lane & 7) << 3;

  f32x4 acc1[4][4] = {}, acc2[4][4] = {};
  short8 bf1k[2][4], bf2k[2][4];          // bf sets per kk (static idx only)
  short8 af00, af01, af10, af11;          // m01 / m23 ping-pong pairs

  auto stA2 = [&](int slot, int kt, int i0) {   // 2 A-issues
    const int k0 = kt * 64;
    #pragma unroll
    for (int i = 0; i < 2; i++) {
      const int chunk = w * 4 + i0 + i;
      gload16(&XB[(size_t)(m0 + chunk * 8 + srow) * HID + k0 + scol],
              &lA[slot][chunk * 8][0]);
    }
  };
  auto stB1s = [&](int slot, int kt) {          // 2 B1-issues
    const int k0 = kt * 64;
    #pragma unroll
    for (int i = 0; i < 2; i++) {
      const int chunk = w * 2 + i;
      gload16(&W1T[(size_t)(n0 + chunk * 8 + srow) * HID + k0 + scol],
              &lB1[slot][chunk * 8][0]);
    }
  };
  auto stB2s = [&](int slot, int kt) {          // 2 B2-issues
    const int k0 = kt * 64;
    #pragma unroll
    for (int i = 0; i < 2; i++) {
      const int chunk = w * 2 + i;
      gload16(&W2T[(size_t)(n0 + chunk * 8 + srow) * HID + k0 + scol],
              &lB2[slot][chunk * 8][0]);
    }
  };
  auto rdA = [&](int s, int m, int kk) -> short8 {
    const int lk = (kk * 32 + lkhi) ^ swz;
    return *reinterpret_cast<const short8*>(&lA[s][wr + m * 16 + lrow][lk]);
  };

#define RDBF(S, KK)                                                                   \
  _Pragma("unroll")                                                                   \
  for (int n = 0; n < 4; n++) {                                                       \
    const int lk = ((KK) * 32 + lkhi) ^ swz;                                          \
    bf1k[KK][n] = *reinterpret_cast<const short8*>(&lB1[S][wc + n * 16 + lrow][lk]);  \
    bf2k[KK][n] = *reinterpret_cast<const short8*>(&lB2[S][wc + n * 16 + lrow][lk]);  \
  }
#define MM16(MB, A0, A1, KB)                                                                           \
  _Pragma("unroll")                                                                                    \
  for (int n = 0; n < 4; n++) {                                                                        \
    acc1[MB][n]     = __builtin_amdgcn_mfma_f32_16x16x32_bf16(A0, bf1k[KB][n], acc1[MB][n], 0, 0, 0);     \
    acc1[MB + 1][n] = __builtin_amdgcn_mfma_f32_16x16x32_bf16(A1, bf1k[KB][n], acc1[MB + 1][n], 0, 0, 0); \
    acc2[MB][n]     = __builtin_amdgcn_mfma_f32_16x16x32_bf16(A0, bf2k[KB][n], acc2[MB][n], 0, 0, 0);     \
    acc2[MB + 1][n] = __builtin_amdgcn_mfma_f32_16x16x32_bf16(A1, bf2k[KB][n], acc2[MB + 1][n], 0, 0, 0); \
  }
// K-tile: compute slot S (K=64, 4 quadrants), stage tile TS into slot SN.
// Quadrant reads are hoisted one barrier-phase ahead of their MFMA cluster.
#define GHALF(S, SN, TS)                                    \
  stA2(SN, TS, 0);                                          \
  VMWAIT(2);                                                \
  BAR();                                                    \
  af00 = rdA(S, 0, 0); af01 = rdA(S, 1, 0);                 \
  RDBF(S, 0);                                               \
  af10 = rdA(S, 2, 0); af11 = rdA(S, 3, 0);                 \
  stA2(SN, TS, 2);                                          \
  BAR();                                                    \
  PRIO1; MM16(0, af00, af01, 0); PRIO0;                     \
  BAR();                                                    \
  af00 = rdA(S, 0, 1); af01 = rdA(S, 1, 1);                 \
  RDBF(S, 1);                                               \
  stB1s(SN, TS);                                            \
  BAR();                                                    \
  PRIO1; MM16(2, af10, af11, 0); PRIO0;                     \
  BAR();                                                    \
  af10 = rdA(S, 2, 1); af11 = rdA(S, 3, 1);                 \
  stB2s(SN, TS);                                            \
  BAR();                                                    \
  PRIO1; MM16(0, af00, af01, 1); PRIO0;                     \
  BAR();                                                    \
  PRIO1; MM16(2, af10, af11, 1); PRIO0;                     \
  BAR();

  // prologue: stage tile 0 into slot 0 (8 issues)
  stA2(0, 0, 0); stA2(0, 0, 2); stB1s(0, 0); stB2s(0, 0);

  #pragma unroll 1
  for (int i = 0; i < 8; i++) {
    const int tb = 2 * i + 1;
    const int tn = (i < 7) ? 2 * i + 2 : 15;   // last iter: harmless restage
    GHALF(0, 1, tb)    // compute tile 2i   (slot0), stage tile 2i+1 -> slot1
    GHALF(1, 0, tn)    // compute tile 2i+1 (slot1), stage tile 2i+2 -> slot0
  }
  VMWAIT(0);
#undef GHALF
#undef MM16
#undef RDBF

  // epilogue: bias + reasoning-mask blend; C/D: col=lane&15, row=(lane>>4)*4+r
  #pragma unroll
  for (int m = 0; m < 4; m++) {
    const int rbase = m0 + wr + m * 16 + ((lane >> 4) << 2);
    #pragma unroll
    for (int n = 0; n < 4; n++) {
      const int col = n0 + wc + n * 16 + lrow;
      const float bias1 = B1b[col];
      const float bias2 = B2b[col];
      #pragma unroll
      for (int r = 0; r < 4; r++) {
        const int row = rbase + r;
        const float mk = MASK[row];
        const float val = (acc1[m][n][r] + bias1) * (1.f - mk) +
                          (acc2[m][n][r] + bias2) * mk;
        OUT[(size_t)row * HID + col] = __float2bfloat16(val);
      }
    }
  }
}

// ---------------- plain 8-phase GEMM (single B): V-proj and out-proj --------
// BM=256 BN=128 BK=64, 512 thr, counted vmcnt(3), READ-AHEAD (all frag reads
// up-front per K-tile, MFMA clusters after).
template<bool OUTF32>
__global__ __launch_bounds__(512, 2) void plain8_kernel(
    const short* __restrict__ A, const short* __restrict__ WT,
    const float* __restrict__ BIAS, void* __restrict__ OUTv)
{
  __shared__ short lA[2][256][64];    // 64 KB
  __shared__ short lB[2][128][64];    // 32 KB

  const int m0 = blockIdx.x * 256, n0 = blockIdx.y * 128;
  const int tid = threadIdx.x, lane = tid & 63, w = tid >> 6;
  const int wr = (w >> 1) * 64, wc = (w & 1) * 64;
  const int lrow = lane & 15, lkhi = (lane >> 4) << 3;
  const int swz = (lrow & 7) << 3;
  const int srow = lane >> 3, scol = (lane & 7) << 3;

  f32x4 acc[4][4] = {};
  short8 paf[2][4], pbf[2][4];        // per-kk fragment sets (static idx only)

  auto stTrip = [&](int slot, int kt, int t) {  // t=0 -> A{0,1,2}; t=1 -> A3,B0,B1
    const int k0 = kt * 64;
    if (t == 0) {
      #pragma unroll
      for (int i = 0; i < 3; i++) {
        const int chunk = w * 4 + i;
        gload16(&A[(size_t)(m0 + chunk * 8 + srow) * HID + k0 + scol],
                &lA[slot][chunk * 8][0]);
      }
    } else {
      const int chunk = w * 4 + 3;
      gload16(&A[(size_t)(m0 + chunk * 8 + srow) * HID + k0 + scol],
              &lA[slot][chunk * 8][0]);
      #pragma unroll
      for (int i = 0; i < 2; i++) {
        const int bchunk = w * 2 + i;
        gload16(&WT[(size_t)(n0 + bchunk * 8 + srow) * HID + k0 + scol],
                &lB[slot][bchunk * 8][0]);
      }
    }
  };

#define RDP(S, KK)                                                                    \
  _Pragma("unroll")                                                                   \
  for (int m = 0; m < 4; m++) {                                                       \
    const int lk = ((KK) * 32 + lkhi) ^ swz;                                          \
    paf[KK][m] = *reinterpret_cast<const short8*>(&lA[S][wr + m * 16 + lrow][lk]);    \
    pbf[KK][m] = *reinterpret_cast<const short8*>(&lB[S][wc + m * 16 + lrow][lk]);    \
  }
#define PMM16(KK)                                                                     \
  _Pragma("unroll")                                                                   \
  for (int m = 0; m < 4; m++)                                                         \
    _Pragma("unroll")                                                                 \
    for (int n = 0; n < 4; n++)                                                       \
      acc[m][n] = __builtin_amdgcn_mfma_f32_16x16x32_bf16(paf[KK][m], pbf[KK][n], acc[m][n], 0, 0, 0);
#define PHALF(S, SN, TS)        \
  stTrip(SN, TS, 0);            \
  VMWAIT(3);                    \
  BAR();                        \
  RDP(S, 0)                     \
  RDP(S, 1)                     \
  stTrip(SN, TS, 1);            \
  BAR();                        \
  PRIO1; PMM16(0) PRIO0;        \
  BAR();                        \
  PRIO1; PMM16(1) PRIO0;        \
  BAR();

  stTrip(0, 0, 0); stTrip(0, 0, 1);   // prologue: tile 0 -> slot 0 (6 issues)

  #pragma unroll 1
  for (int i = 0; i < 8; i++) {
    const int tb = 2 * i + 1;
    const int tn = (i < 7) ? 2 * i + 2 : 15;
    PHALF(0, 1, tb)
    PHALF(1, 0, tn)
  }
  VMWAIT(0);
#undef PHALF
#undef PMM16
#undef RDP

  #pragma unroll
  for (int m = 0; m < 4; m++) {
    const int rbase = m0 + wr + m * 16 + ((lane >> 4) << 2);
    #pragma unroll
    for (int n = 0; n < 4; n++) {
      const int col = n0 + wc + n * 16 + lrow;
      const float bias = BIAS[col];
      #pragma unroll
      for (int r = 0; r < 4; r++) {
        const float val = acc[m][n][r] + bias;
        const size_t oidx = (size_t)(rbase + r) * HID + col;
        if (OUTF32) ((float*)OUTv)[oidx] = val;
        else ((__hip_bfloat16*)OUTv)[oidx] = __float2bfloat16(val);
      }
    }
  }
}

// ---------------- per-token 16x16 cross-head attention ----------------------
// out row = b*2048 + h*128 + s/16, col = (s%16)*64 + d, stored with the
// 64-block swizzle (d ^= (row&7)<<3) so the final GEMM can global_load_lds it.
__global__ __launch_bounds__(256) void attn_kernel(
    const __hip_bfloat16* __restrict__ Q, const __hip_bfloat16* __restrict__ K,
    const __hip_bfloat16* __restrict__ V, __hip_bfloat16* __restrict__ O)
{
  const int t = blockIdx.x;
  const int b = t >> 11, s = t & 2047;
  __shared__ float sQ[16][68], sK[16][68], sV[16][68];
  __shared__ float sA[16][17];
  const int tid = threadIdx.x;
  const size_t tb = (size_t)t * HID;

  {
    const int h = tid >> 4, d0 = (tid & 15) << 2;
    const int o = (h << 6) + d0;
    const short4v qv = *reinterpret_cast<const short4v*>(&((const short*)Q)[tb + o]);
    const short4v kv = *reinterpret_cast<const short4v*>(&((const short*)K)[tb + o]);
    const short4v vv = *reinterpret_cast<const short4v*>(&((const short*)V)[tb + o]);
    #pragma unroll
    for (int j = 0; j < 4; j++) {
      sQ[h][d0 + j] = bs2f(qv[j]);
      sK[h][d0 + j] = bs2f(kv[j]);
      sV[h][d0 + j] = bs2f(vv[j]);
    }
  }
  __syncthreads();

  const int h = tid >> 4, e = tid & 15;
  float sc = 0.f;
  #pragma unroll
  for (int d = 0; d < 64; d++) sc += sQ[h][d] * sK[e][d];
  sc *= 0.125f;

  float mx = sc;
  mx = fmaxf(mx, __shfl_xor(mx, 1));
  mx = fmaxf(mx, __shfl_xor(mx, 2));
  mx = fmaxf(mx, __shfl_xor(mx, 4));
  mx = fmaxf(mx, __shfl_xor(mx, 8));
  const float p = __expf(sc - mx);
  float sm = p;
  sm += __shfl_xor(sm, 1);
  sm += __shfl_xor(sm, 2);
  sm += __shfl_xor(sm, 4);
  sm += __shfl_xor(sm, 8);
  sA[h][e] = p / sm;
  __syncthreads();

  const int row7 = (s >> 4) & 7;
  const size_t ob = ((size_t)b * 2048 + (s >> 4)) * HID + ((size_t)(s & 15) << 6);
  {
    const int hh = tid >> 4, d4 = (tid & 15) << 2;
    f32x4 o = {0.f, 0.f, 0.f, 0.f};
    #pragma unroll
    for (int e2 = 0; e2 < 16; e2++) {
      const float a = sA[hh][e2];
      #pragma unroll
      for (int j = 0; j < 4; j++) o[j] += a * sV[e2][d4 + j];
    }
    short4v ov;
    #pragma unroll
    for (int j = 0; j < 4; j++) ov[j] = f2bs(o[j]);
    *reinterpret_cast<short4v*>(
        &((short*)O)[ob + (size_t)hh * 128 * HID + (d4 ^ (row7 << 3))]) = ov;
  }
}

extern "C" void kernel_launch(void* const* d_in, const int* in_sizes, int n_in,
                              void* d_out, int out_size, void* d_ws, size_t ws_size,
                              hipStream_t stream) {
  (void)in_sizes; (void)n_in; (void)out_size; (void)ws_size;
  const float* x   = (const float*)d_in[0];
  const float* rm  = (const float*)d_in[1];
  const float* Wq  = (const float*)d_in[2];
  const float* bq  = (const float*)d_in[3];
  const float* Wk  = (const float*)d_in[4];
  const float* bk  = (const float*)d_in[5];
  const float* Wv  = (const float*)d_in[6];
  const float* bv  = (const float*)d_in[7];
  const float* Wqr = (const float*)d_in[8];
  const float* bqr = (const float*)d_in[9];
  const float* Wkr = (const float*)d_in[10];
  const float* bkr = (const float*)d_in[11];
  const float* Wo  = (const float*)d_in[12];
  const float* bo  = (const float*)d_in[13];

  // ws: [0:12M) WT (Wq,Wqr,Wk,Wkr,Wv,Wo) | [12:28M) qg | [28:44M) vv | [44:60M) ar
  char* ws = (char*)d_ws;
  short* wt = (short*)ws;
  __hip_bfloat16* qg = (__hip_bfloat16*)(ws + 12u * 1024 * 1024);
  __hip_bfloat16* vv = (__hip_bfloat16*)(ws + 28u * 1024 * 1024);
  __hip_bfloat16* ar = (__hip_bfloat16*)(ws + 44u * 1024 * 1024);
  // d_out (32 MiB fp32) doubles as scratch until the final GEMM rewrites it:
  short* xb = (short*)d_out;                                        // [0:16M)
  __hip_bfloat16* kg = (__hip_bfloat16*)((char*)d_out + 16u * 1024 * 1024);  // [16:32M)

  prep_kernel<<<dim3(5632), 256, 0, stream>>>(Wq, Wqr, Wk, Wkr, Wv, Wo, x, wt, xb);
  gated8_kernel<<<dim3(32, 8, 2), 512, 0, stream>>>(xb, wt, bq, bqr, bk, bkr, rm, qg, kg);
  plain8_kernel<false><<<dim3(32, 8), 512, 0, stream>>>(xb, wt + (size_t)4 * WT_ELEMS, bv, vv);
  attn_kernel<<<dim3(NTOK), 256, 0, stream>>>(qg, kg, vv, ar);
  plain8_kernel<true><<<dim3(32, 8), 512, 0, stream>>>((const short*)ar,
                                                       wt + (size_t)5 * WT_ELEMS, bo, d_out);
}

// Round 6
// 152.328 us; speedup vs baseline: 4.1935x; 1.0876x over previous
//
#include <hip/hip_runtime.h>
#include <hip/hip_bf16.h>

// ReasoningMultiHeadAttention: B=4 S=2048 HID=1024 NH=16 DH=64. All I/O fp32.
// prep: 6x W -> bf16 W^T pre-swizzled (wt, ws) ; x -> bf16 xb pre-swizzled (in d_out!)
// gated8: balanced-phase counted-vmcnt GEMM, dual-B: qg (ws), kg (d_out hi)
//   4 phases/K-tile, each: {<=8 ds_reads + stage issues} BAR {16 MFMA} BAR
// plain8<bf16>: xb @ WvT + bv -> vv (ws)   (2 phases/K-tile, 8 reads + 16 MFMA)
// attn: per-token 16x16 cross-head attn -> ar (ws, swizzled+scrambled)
// plain8<f32>: ar @ WoT + bo -> d_out (overwrites xb/kg scratch, all dead)
// ws usage: [0:12M wt][12:28M qg][28:44M vv][44:60M ar] = 60 MB
// d_out scratch: [0:16M xb][16:32M kg] until final GEMM rewrites all of d_out.

typedef __attribute__((ext_vector_type(8))) short short8;
typedef __attribute__((ext_vector_type(4))) short short4v;
typedef __attribute__((ext_vector_type(4))) float f32x4;

#define HID 1024
#define NTOK 8192
#define WT_ELEMS (1024 * 1024)

__device__ __forceinline__ short f2bs(float f) {
  __hip_bfloat16 h = __float2bfloat16(f);
  return *reinterpret_cast<short*>(&h);
}
__device__ __forceinline__ float bs2f(short s) {
  __hip_bfloat16 h;
  *reinterpret_cast<short*>(&h) = s;
  return __bfloat162float(h);
}
__device__ __forceinline__ void gload16(const void* g, void* l) {
  __builtin_amdgcn_global_load_lds(
      (const __attribute__((address_space(1))) void*)g,
      (__attribute__((address_space(3))) void*)l, 16, 0, 0);
}

#define BAR() asm volatile("s_barrier" ::: "memory")
#define VMWAIT(N) asm volatile("s_waitcnt vmcnt(" #N ")" ::: "memory")
#define LGKM0 do { asm volatile("s_waitcnt lgkmcnt(0)" ::: "memory"); \
                   __builtin_amdgcn_sched_barrier(0); } while (0)
#define SCB __builtin_amdgcn_sched_barrier(0)
#define PRIO1 __builtin_amdgcn_s_setprio(1)
#define PRIO0 __builtin_amdgcn_s_setprio(0)
#define MFMA16x16 __builtin_amdgcn_mfma_f32_16x16x32_bf16

// ---------------- prep: W transposes (z<6) + x fp32->bf16 convert ----------
// WT[n][ (k&~63) | ((k&63) ^ ((n&7)<<3)) ] = bf16(W[k][n])
// XB[row][ (k&~63) | ((k&63) ^ ((row&7)<<3)) ] = bf16(x[row][k])
__global__ __launch_bounds__(256) void prep_kernel(
    const float* __restrict__ W0, const float* __restrict__ W1,
    const float* __restrict__ W2, const float* __restrict__ W3,
    const float* __restrict__ W4, const float* __restrict__ W5,
    const float* __restrict__ X, short* __restrict__ WT, short* __restrict__ XB)
{
  __shared__ short sT[64][68];
  const int bid = blockIdx.x, tid = threadIdx.x;
  if (bid < 1536) {
    const int z = bid >> 8, rem = bid & 255;
    const float* W = z == 0 ? W0 : z == 1 ? W1 : z == 2 ? W2 : z == 3 ? W3
                   : z == 4 ? W4 : W5;
    short* OUT = WT + (size_t)z * WT_ELEMS;
    const int k0 = (rem & 15) * 64, n0 = (rem >> 4) * 64;
    #pragma unroll
    for (int i = 0; i < 4; i++) {
      const int li = tid + i * 256;
      const int kr = li >> 4, c4 = (li & 15) << 2;
      const f32x4 wv = *reinterpret_cast<const f32x4*>(&W[(size_t)(k0 + kr) * HID + n0 + c4]);
      short4v s4;
      #pragma unroll
      for (int j = 0; j < 4; j++) s4[j] = f2bs(wv[j]);
      *reinterpret_cast<short4v*>(&sT[kr][c4]) = s4;
    }
    __syncthreads();
    #pragma unroll
    for (int i = 0; i < 4; i++) {
      const int li = tid + i * 256;
      const int nr = li >> 4, k4 = (li & 15) << 2;
      short4v o;
      #pragma unroll
      for (int j = 0; j < 4; j++) o[j] = sT[k4 + j][nr];
      const int kcol = (k0 + k4) ^ ((nr & 7) << 3);
      *reinterpret_cast<short4v*>(&OUT[(size_t)(n0 + nr) * HID + kcol]) = o;
    }
  } else {
    const int gid = (bid - 1536) * 256 + tid;      // 0..1048575
    const int row = gid >> 7, kc = (gid & 127) << 3;
    const f32x4 a = *reinterpret_cast<const f32x4*>(&X[(size_t)row * HID + kc]);
    const f32x4 b = *reinterpret_cast<const f32x4*>(&X[(size_t)row * HID + kc + 4]);
    short8 s;
    #pragma unroll
    for (int j = 0; j < 4; j++) { s[j] = f2bs(a[j]); s[4 + j] = f2bs(b[j]); }
    const int phys = (kc & ~63) | ((kc & 63) ^ ((row & 7) << 3));
    *reinterpret_cast<short8*>(&XB[(size_t)row * HID + phys]) = s;
  }
}

// ---------------- gated GEMM: z=0 -> qg, z=1 -> kg --------------------------
// BM=256 BN=128 BK=64, 512 thr (8 waves, 4M x 2N), dual-B.
// 4 balanced phases per K-tile: reads {8,4,8,4}/wave vs 16-MFMA clusters.
__global__ __launch_bounds__(512, 2) void gated8_kernel(
    const short* __restrict__ XB, const short* __restrict__ WTbase,
    const float* __restrict__ bq, const float* __restrict__ bqr,
    const float* __restrict__ bk, const float* __restrict__ bkr,
    const float* __restrict__ MASK,
    __hip_bfloat16* __restrict__ qg, __hip_bfloat16* __restrict__ kg)
{
  __shared__ short lA[2][256][64];    // 64 KB
  __shared__ short lB1[2][128][64];   // 32 KB
  __shared__ short lB2[2][128][64];   // 32 KB

  const int z = blockIdx.z;
  const short* W1T = WTbase + (size_t)(2 * z) * WT_ELEMS;
  const short* W2T = W1T + WT_ELEMS;
  const float* B1b = z ? bk : bq;
  const float* B2b = z ? bkr : bqr;
  __hip_bfloat16* OUT = z ? kg : qg;

  const int m0 = blockIdx.x * 256, n0 = blockIdx.y * 128;
  const int tid = threadIdx.x, lane = tid & 63, w = tid >> 6;
  const int wr = (w >> 1) * 64, wc = (w & 1) * 64;
  const int lrow = lane & 15, lkhi = (lane >> 4) << 3;
  const int swz = (lrow & 7) << 3;
  const int srow = lane >> 3, scol = (lane & 7) << 3;

  f32x4 acc1[4][4] = {}, acc2[4][4] = {};
  short8 bf1k[4], bf2k[4];
  short8 af0, af1, af2, af3;

  auto stA2 = [&](int slot, int kt, int i0) {   // 2 A-issues
    const int k0 = kt * 64;
    #pragma unroll
    for (int i = 0; i < 2; i++) {
      const int chunk = w * 4 + i0 + i;
      gload16(&XB[(size_t)(m0 + chunk * 8 + srow) * HID + k0 + scol],
              &lA[slot][chunk * 8][0]);
    }
  };
  auto stB1s = [&](int slot, int kt) {          // 2 B1-issues
    const int k0 = kt * 64;
    #pragma unroll
    for (int i = 0; i < 2; i++) {
      const int chunk = w * 2 + i;
      gload16(&W1T[(size_t)(n0 + chunk * 8 + srow) * HID + k0 + scol],
              &lB1[slot][chunk * 8][0]);
    }
  };
  auto stB2s = [&](int slot, int kt) {          // 2 B2-issues
    const int k0 = kt * 64;
    #pragma unroll
    for (int i = 0; i < 2; i++) {
      const int chunk = w * 2 + i;
      gload16(&W2T[(size_t)(n0 + chunk * 8 + srow) * HID + k0 + scol],
              &lB2[slot][chunk * 8][0]);
    }
  };
  auto rdA = [&](int s, int m, int kk) -> short8 {
    const int lk = (kk * 32 + lkhi) ^ swz;
    return *reinterpret_cast<const short8*>(&lA[s][wr + m * 16 + lrow][lk]);
  };

#define RDB1(S, KK)                                                                   \
  _Pragma("unroll")                                                                   \
  for (int n = 0; n < 4; n++) {                                                       \
    const int lk = ((KK) * 32 + lkhi) ^ swz;                                          \
    bf1k[n] = *reinterpret_cast<const short8*>(&lB1[S][wc + n * 16 + lrow][lk]);      \
  }
#define RDB2(S, KK)                                                                   \
  _Pragma("unroll")                                                                   \
  for (int n = 0; n < 4; n++) {                                                       \
    const int lk = ((KK) * 32 + lkhi) ^ swz;                                          \
    bf2k[n] = *reinterpret_cast<const short8*>(&lB2[S][wc + n * 16 + lrow][lk]);      \
  }
#define MM16A                                                             \
  _Pragma("unroll")                                                       \
  for (int n = 0; n < 4; n++) {                                           \
    acc1[0][n] = MFMA16x16(af0, bf1k[n], acc1[0][n], 0, 0, 0);            \
    acc1[1][n] = MFMA16x16(af1, bf1k[n], acc1[1][n], 0, 0, 0);            \
    acc1[2][n] = MFMA16x16(af2, bf1k[n], acc1[2][n], 0, 0, 0);            \
    acc1[3][n] = MFMA16x16(af3, bf1k[n], acc1[3][n], 0, 0, 0);            \
  }
#define MM16B                                                             \
  _Pragma("unroll")                                                       \
  for (int n = 0; n < 4; n++) {                                           \
    acc2[0][n] = MFMA16x16(af0, bf2k[n], acc2[0][n], 0, 0, 0);            \
    acc2[1][n] = MFMA16x16(af1, bf2k[n], acc2[1][n], 0, 0, 0);            \
    acc2[2][n] = MFMA16x16(af2, bf2k[n], acc2[2][n], 0, 0, 0);            \
    acc2[3][n] = MFMA16x16(af3, bf2k[n], acc2[3][n], 0, 0, 0);            \
  }
// K-tile: 4 balanced phases. Stage issues 4+4 in P1/P2; wait at end of P4
// (>= 2 phases after last issue -> pre-satisfied, no stall).
#define GTILE(S, SN, TS)                                                 \
  /* P1: 8 reads + 4 stage issues | MM acc1 kk0 */                       \
  af0 = rdA(S, 0, 0); af1 = rdA(S, 1, 0);                                \
  af2 = rdA(S, 2, 0); af3 = rdA(S, 3, 0);                                \
  RDB1(S, 0);                                                            \
  stA2(SN, TS, 0); stA2(SN, TS, 2);                                      \
  BAR(); LGKM0;                                                          \
  PRIO1; MM16A PRIO0; SCB;                                               \
  BAR();                                                                 \
  /* P2: 4 reads + 4 stage issues | MM acc2 kk0 */                       \
  RDB2(S, 0);                                                            \
  stB1s(SN, TS); stB2s(SN, TS);                                          \
  BAR(); LGKM0;                                                          \
  PRIO1; MM16B PRIO0; SCB;                                               \
  BAR();                                                                 \
  /* P3: 8 reads | MM acc1 kk1 */                                        \
  af0 = rdA(S, 0, 1); af1 = rdA(S, 1, 1);                                \
  af2 = rdA(S, 2, 1); af3 = rdA(S, 3, 1);                                \
  RDB1(S, 1);                                                            \
  BAR(); LGKM0;                                                          \
  PRIO1; MM16A PRIO0; SCB;                                               \
  BAR();                                                                 \
  /* P4: 4 reads | MM acc2 kk1 | wait staged tile */                     \
  RDB2(S, 1);                                                            \
  BAR(); LGKM0;                                                          \
  PRIO1; MM16B PRIO0; SCB;                                               \
  VMWAIT(0);                                                             \
  BAR();

  // prologue: stage tile 0 into slot 0 (8 issues), wait, open
  stA2(0, 0, 0); stA2(0, 0, 2); stB1s(0, 0); stB2s(0, 0);
  VMWAIT(0);
  BAR();

  #pragma unroll 1
  for (int i = 0; i < 8; i++) {
    const int tb = 2 * i + 1;
    const int tn = (i < 7) ? 2 * i + 2 : 15;   // last iter: harmless restage
    GTILE(0, 1, tb)    // compute tile 2i   (slot0), stage tile 2i+1 -> slot1
    GTILE(1, 0, tn)    // compute tile 2i+1 (slot1), stage tile 2i+2 -> slot0
  }
#undef GTILE
#undef MM16A
#undef MM16B
#undef RDB1
#undef RDB2

  // epilogue: bias + reasoning-mask blend; C/D: col=lane&15, row=(lane>>4)*4+r
  #pragma unroll
  for (int m = 0; m < 4; m++) {
    const int rbase = m0 + wr + m * 16 + ((lane >> 4) << 2);
    #pragma unroll
    for (int n = 0; n < 4; n++) {
      const int col = n0 + wc + n * 16 + lrow;
      const float bias1 = B1b[col];
      const float bias2 = B2b[col];
      #pragma unroll
      for (int r = 0; r < 4; r++) {
        const int row = rbase + r;
        const float mk = MASK[row];
        const float val = (acc1[m][n][r] + bias1) * (1.f - mk) +
                          (acc2[m][n][r] + bias2) * mk;
        OUT[(size_t)row * HID + col] = __float2bfloat16(val);
      }
    }
  }
}

// ---------------- plain GEMM (single B): V-proj and out-proj ----------------
// BM=256 BN=128 BK=64, 512 thr, 2 balanced phases/K-tile (8 reads vs 16 MFMA).
template<bool OUTF32>
__global__ __launch_bounds__(512, 2) void plain8_kernel(
    const short* __restrict__ A, const short* __restrict__ WT,
    const float* __restrict__ BIAS, void* __restrict__ OUTv)
{
  __shared__ short lA[2][256][64];    // 64 KB
  __shared__ short lB[2][128][64];    // 32 KB

  const int m0 = blockIdx.x * 256, n0 = blockIdx.y * 128;
  const int tid = threadIdx.x, lane = tid & 63, w = tid >> 6;
  const int wr = (w >> 1) * 64, wc = (w & 1) * 64;
  const int lrow = lane & 15, lkhi = (lane >> 4) << 3;
  const int swz = (lrow & 7) << 3;
  const int srow = lane >> 3, scol = (lane & 7) << 3;

  f32x4 acc[4][4] = {};
  short8 paf[4], pbf[4];

  auto stTrip = [&](int slot, int kt, int t) {  // t=0 -> A{0,1,2}; t=1 -> A3,B0,B1
    const int k0 = kt * 64;
    if (t == 0) {
      #pragma unroll
      for (int i = 0; i < 3; i++) {
        const int chunk = w * 4 + i;
        gload16(&A[(size_t)(m0 + chunk * 8 + srow) * HID + k0 + scol],
                &lA[slot][chunk * 8][0]);
      }
    } else {
      const int chunk = w * 4 + 3;
      gload16(&A[(size_t)(m0 + chunk * 8 + srow) * HID + k0 + scol],
              &lA[slot][chunk * 8][0]);
      #pragma unroll
      for (int i = 0; i < 2; i++) {
        const int bchunk = w * 2 + i;
        gload16(&WT[(size_t)(n0 + bchunk * 8 + srow) * HID + k0 + scol],
                &lB[slot][bchunk * 8][0]);
      }
    }
  };

#define RDP(S, KK)                                                                    \
  _Pragma("unroll")                                                                   \
  for (int m = 0; m < 4; m++) {                                                       \
    const int lk = ((KK) * 32 + lkhi) ^ swz;                                          \
    paf[m] = *reinterpret_cast<const short8*>(&lA[S][wr + m * 16 + lrow][lk]);        \
    pbf[m] = *reinterpret_cast<const short8*>(&lB[S][wc + m * 16 + lrow][lk]);        \
  }
#define PMM16                                                                         \
  _Pragma("unroll")                                                                   \
  for (int m = 0; m < 4; m++)                                                         \
    _Pragma("unroll")                                                                 \
    for (int n = 0; n < 4; n++)                                                       \
      acc[m][n] = MFMA16x16(paf[m], pbf[n], acc[m][n], 0, 0, 0);
#define PTILE(S, SN, TS)        \
  /* P1 */                      \
  RDP(S, 0)                     \
  stTrip(SN, TS, 0);            \
  BAR(); LGKM0;                 \
  PRIO1; PMM16 PRIO0; SCB;      \
  BAR();                        \
  /* P2 */                      \
  RDP(S, 1)                     \
  stTrip(SN, TS, 1);            \
  BAR(); LGKM0;                 \
  PRIO1; PMM16 PRIO0; SCB;      \
  VMWAIT(0);                    \
  BAR();

  stTrip(0, 0, 0); stTrip(0, 0, 1);   // prologue: tile 0 -> slot 0 (6 issues)
  VMWAIT(0);
  BAR();

  #pragma unroll 1
  for (int i = 0; i < 8; i++) {
    const int tb = 2 * i + 1;
    const int tn = (i < 7) ? 2 * i + 2 : 15;
    PTILE(0, 1, tb)
    PTILE(1, 0, tn)
  }
#undef PTILE
#undef PMM16
#undef RDP

  #pragma unroll
  for (int m = 0; m < 4; m++) {
    const int rbase = m0 + wr + m * 16 + ((lane >> 4) << 2);
    #pragma unroll
    for (int n = 0; n < 4; n++) {
      const int col = n0 + wc + n * 16 + lrow;
      const float bias = BIAS[col];
      #pragma unroll
      for (int r = 0; r < 4; r++) {
        const float val = acc[m][n][r] + bias;
        const size_t oidx = (size_t)(rbase + r) * HID + col;
        if (OUTF32) ((float*)OUTv)[oidx] = val;
        else ((__hip_bfloat16*)OUTv)[oidx] = __float2bfloat16(val);
      }
    }
  }
}

// ---------------- per-token 16x16 cross-head attention ----------------------
// out row = b*2048 + h*128 + s/16, col = (s%16)*64 + d, stored with the
// 64-block swizzle (d ^= (row&7)<<3) so the final GEMM can global_load_lds it.
__global__ __launch_bounds__(256) void attn_kernel(
    const __hip_bfloat16* __restrict__ Q, const __hip_bfloat16* __restrict__ K,
    const __hip_bfloat16* __restrict__ V, __hip_bfloat16* __restrict__ O)
{
  const int t = blockIdx.x;
  const int b = t >> 11, s = t & 2047;
  __shared__ float sQ[16][68], sK[16][68], sV[16][68];
  __shared__ float sA[16][17];
  const int tid = threadIdx.x;
  const size_t tb = (size_t)t * HID;

  {
    const int h = tid >> 4, d0 = (tid & 15) << 2;
    const int o = (h << 6) + d0;
    const short4v qv = *reinterpret_cast<const short4v*>(&((const short*)Q)[tb + o]);
    const short4v kv = *reinterpret_cast<const short4v*>(&((const short*)K)[tb + o]);
    const short4v vv = *reinterpret_cast<const short4v*>(&((const short*)V)[tb + o]);
    #pragma unroll
    for (int j = 0; j < 4; j++) {
      sQ[h][d0 + j] = bs2f(qv[j]);
      sK[h][d0 + j] = bs2f(kv[j]);
      sV[h][d0 + j] = bs2f(vv[j]);
    }
  }
  __syncthreads();

  const int h = tid >> 4, e = tid & 15;
  float sc = 0.f;
  #pragma unroll
  for (int d = 0; d < 64; d++) sc += sQ[h][d] * sK[e][d];
  sc *= 0.125f;

  float mx = sc;
  mx = fmaxf(mx, __shfl_xor(mx, 1));
  mx = fmaxf(mx, __shfl_xor(mx, 2));
  mx = fmaxf(mx, __shfl_xor(mx, 4));
  mx = fmaxf(mx, __shfl_xor(mx, 8));
  const float p = __expf(sc - mx);
  float sm = p;
  sm += __shfl_xor(sm, 1);
  sm += __shfl_xor(sm, 2);
  sm += __shfl_xor(sm, 4);
  sm += __shfl_xor(sm, 8);
  sA[h][e] = p / sm;
  __syncthreads();

  const int row7 = (s >> 4) & 7;
  const size_t ob = ((size_t)b * 2048 + (s >> 4)) * HID + ((size_t)(s & 15) << 6);
  {
    const int hh = tid >> 4, d4 = (tid & 15) << 2;
    f32x4 o = {0.f, 0.f, 0.f, 0.f};
    #pragma unroll
    for (int e2 = 0; e2 < 16; e2++) {
      const float a = sA[hh][e2];
      #pragma unroll
      for (int j = 0; j < 4; j++) o[j] += a * sV[e2][d4 + j];
    }
    short4v ov;
    #pragma unroll
    for (int j = 0; j < 4; j++) ov[j] = f2bs(o[j]);
    *reinterpret_cast<short4v*>(
        &((short*)O)[ob + (size_t)hh * 128 * HID + (d4 ^ (row7 << 3))]) = ov;
  }
}

extern "C" void kernel_launch(void* const* d_in, const int* in_sizes, int n_in,
                              void* d_out, int out_size, void* d_ws, size_t ws_size,
                              hipStream_t stream) {
  (void)in_sizes; (void)n_in; (void)out_size; (void)ws_size;
  const float* x   = (const float*)d_in[0];
  const float* rm  = (const float*)d_in[1];
  const float* Wq  = (const float*)d_in[2];
  const float* bq  = (const float*)d_in[3];
  const float* Wk  = (const float*)d_in[4];
  const float* bk  = (const float*)d_in[5];
  const float* Wv  = (const float*)d_in[6];
  const float* bv  = (const float*)d_in[7];
  const float* Wqr = (const float*)d_in[8];
  const float* bqr = (const float*)d_in[9];
  const float* Wkr = (const float*)d_in[10];
  const float* bkr = (const float*)d_in[11];
  const float* Wo  = (const float*)d_in[12];
  const float* bo  = (const float*)d_in[13];

  // ws: [0:12M) WT (Wq,Wqr,Wk,Wkr,Wv,Wo) | [12:28M) qg | [28:44M) vv | [44:60M) ar
  char* ws = (char*)d_ws;
  short* wt = (short*)ws;
  __hip_bfloat16* qg = (__hip_bfloat16*)(ws + 12u * 1024 * 1024);
  __hip_bfloat16* vv = (__hip_bfloat16*)(ws + 28u * 1024 * 1024);
  __hip_bfloat16* ar = (__hip_bfloat16*)(ws + 44u * 1024 * 1024);
  // d_out (32 MiB fp32) doubles as scratch until the final GEMM rewrites it:
  short* xb = (short*)d_out;                                        // [0:16M)
  __hip_bfloat16* kg = (__hip_bfloat16*)((char*)d_out + 16u * 1024 * 1024);  // [16:32M)

  prep_kernel<<<dim3(5632), 256, 0, stream>>>(Wq, Wqr, Wk, Wkr, Wv, Wo, x, wt, xb);
  gated8_kernel<<<dim3(32, 8, 2), 512, 0, stream>>>(xb, wt, bq, bqr, bk, bkr, rm, qg, kg);
  plain8_kernel<false><<<dim3(32, 8), 512, 0, stream>>>(xb, wt + (size_t)4 * WT_ELEMS, bv, vv);
  attn_kernel<<<dim3(NTOK), 256, 0, stream>>>(qg, kg, vv, ar);
  plain8_kernel<true><<<dim3(32, 8), 512, 0, stream>>>((const short*)ar,
                                                       wt + (size_t)5 * WT_ELEMS, bo, d_out);
}